// Round 9
// baseline (35623.584 us; speedup 1.0000x reference)
//
#include <hip/hip_runtime.h>
#include <math.h>

// ---------------- ws layout (float offsets), ~108.3 MiB used ----------------
// c2ch : 8*48*130*114                 [        0,  5690880)   chunk-local
// c3p  : 8*96*128*57 (rotating chunk) [  5690880, 11294208)
// ac   : 4096*768                     [ 11294208, 14439936)
// A1   : 512*24576                    [ 14439936, 27022848)
// st   : xbuf 12288 | hbuf 12288 | slt 2816 | sy 8208
//                                     [ 27022848, 27058448)
// psy  : prologue barrier lines       [ 27058448, 27066656)
// rdy  : 4 chunk-ready flags (+pad)   [ 27066656, 27066672)
#define OF_C2CH 0u
#define OF_C3P  5690880u
#define OF_AC   11294208u
#define OF_A1   14439936u
#define OF_ST   27022848u
#define OF_PSY  27058448u
#define OF_RDY  27066656u

__device__ __forceinline__ float sigm(float x){ return 1.0f / (1.0f + expf(-x)); }

// Fine-grained coherent access: bypasses L1/L2, served at the coherence
// point — cross-XCD visible without cache flushes.
// Sync regime (empirically settled over R1..R8):
//   * ALL cross-WG intermediate data (h1, h2, c2ch, c3p, ac, A1): coherent
//     cstore/cload ordered by the relaxed 2-hop barrier (R1/R6-proven).
//     R8 FAILED using plain cached stores for prologue intermediates —
//     per-XCD L2s are not coherent and the barrier doesn't flush.
//   * Immutable inputs (mel, weights): plain cached (kernel-launch acquire).
//   * argmax slots: {tag|value} u64 atoms.
//   * NO cache-maintenance instructions anywhere (no fence-emitted
//     buffer_inv that could discard co-resident WGs' dirty out[] lines).
__device__ __forceinline__ void cstore(float* p, float v){
  union { float f; unsigned u; } c; c.f = v;
  __hip_atomic_store((unsigned*)p, c.u, __ATOMIC_RELAXED,
                     __HIP_MEMORY_SCOPE_SYSTEM);
}
__device__ __forceinline__ float cloadf(const float* p){
  unsigned u = __hip_atomic_load((const unsigned*)p, __ATOMIC_RELAXED,
                                 __HIP_MEMORY_SCOPE_SYSTEM);
  union { unsigned u; float f; } c; c.u = u; return c.f;
}
__device__ __forceinline__ void cload64(const float* p, float& a, float& b){
  unsigned long long u = __hip_atomic_load((const unsigned long long*)p,
                          __ATOMIC_RELAXED, __HIP_MEMORY_SCOPE_SYSTEM);
  union { unsigned long long u; float f[2]; } c; c.u = u;
  a = c.f[0]; b = c.f[1];
}
__device__ __forceinline__ unsigned cloadu(const unsigned* p){
  return __hip_atomic_load(p, __ATOMIC_RELAXED, __HIP_MEMORY_SCOPE_SYSTEM);
}
__device__ __forceinline__ unsigned long long cloadu64(const void* p){
  return __hip_atomic_load((const unsigned long long*)p, __ATOMIC_RELAXED,
                           __HIP_MEMORY_SCOPE_SYSTEM);
}
__device__ __forceinline__ void cstoreu64(void* p, unsigned long long v){
  __hip_atomic_store((unsigned long long*)p, v, __ATOMIC_RELAXED,
                     __HIP_MEMORY_SCOPE_SYSTEM);
}

// 2-hop grid barrier over 256 agents (R1-proven ordering for coherent data):
//   arrival slots sy[16 + id*16]   (writer=id, reader=id255)
//   flag copies   sy[4112 + id*16] (writer=id255, reader=id)
#define SLOT 16
#define FLG  4112
__device__ __forceinline__ void gbar(unsigned* sy, unsigned bar, int id){
  __syncthreads();   // drains vmcnt(0): all coherent data stores retired
  const int tid = threadIdx.x;
  if (tid == 0)
    __hip_atomic_store(&sy[SLOT + id*16], bar, __ATOMIC_RELAXED,
                       __HIP_MEMORY_SCOPE_SYSTEM);
  if (id == 255){
    if (tid < 64){
      for (;;){
        unsigned m0 = cloadu(&sy[SLOT + (4*tid + 0)*16]);
        unsigned m1 = cloadu(&sy[SLOT + (4*tid + 1)*16]);
        unsigned m2 = cloadu(&sy[SLOT + (4*tid + 2)*16]);
        unsigned m3 = cloadu(&sy[SLOT + (4*tid + 3)*16]);
        unsigned a = m0 < m1 ? m0 : m1;
        unsigned b = m2 < m3 ? m2 : m3;
        unsigned mn = a < b ? a : b;
        if (__all(mn >= bar)) break;
        __builtin_amdgcn_s_sleep(1);
      }
    }
    __syncthreads();   // orders poll completion before flag release
    __hip_atomic_store(&sy[FLG + tid*16], bar, __ATOMIC_RELAXED,
                       __HIP_MEMORY_SCOPE_SYSTEM);
  } else {
    if (tid == 0){
      while (cloadu(&sy[FLG + id*16]) < bar)
        __builtin_amdgcn_s_sleep(1);
    }
  }
  __syncthreads();
}

// ================= prologue device bodies (grid-strided) =================

__device__ void conv2f_body(float* SH, int vb, int t0,
    const float* mel, const float* w1, const float* b1, const float* g1,
    const float* be1, const float* m1, const float* v1,
    const float* w2, const float* b2, const float* g2, const float* be2,
    const float* m2, const float* v2, float* c2ch)
{
  float* act  = SH;            // 3*8*240 = 5760
  float* w2s  = SH + 5760;     // 48*8*12 = 4608
  float* mel5 = SH + 10368;    // 5*240 = 1200
  float* w1s  = SH + 11568;    // 48*12 = 576
  float* sc1  = SH + 12144; float* sh1 = SH + 12192;
  float* sc2  = SH + 12240; float* sh2 = SH + 12288;
  int tid = threadIdx.x;
  int b = vb / 130, lt = vb - b*130;
  int t = t0 - 1 + lt;

  int fg = tid % 29, ocg = tid / 29;
  int f0 = fg * 8, oc0 = ocg * 6;

  if (t < 0 || t > 511){
    if (tid < 232){
      for (int o = 0; o < 6; ++o)
        for (int jj = 0; jj < 4; ++jj){
          int fp = fg*4 + jj;
          if (fp < 114)
            cstore(&c2ch[((b*48 + oc0 + o)*130 + lt)*114 + fp], 0.f);
        }
    }
    return;
  }
  __syncthreads();   // LDS reuse guard (previous vb iteration)

  for (int idx = tid; idx < 5*240; idx += 256){
    int rr = idx / 240, w = idx - rr*240;
    int tt = t + rr - 2, f = w - 2;
    mel5[idx] = (tt >= 0 && tt < 512 && f >= 0 && f < 229)
                ? mel[(b*512 + tt)*229 + f] : 0.f;
  }
  for (int idx = tid; idx < 48*12; idx += 256){
    int c = idx / 12, q = idx - c*12;
    int kh = q >> 2, kw = q & 3;
    w1s[idx] = (kw < 3) ? w1[c*9 + kh*3 + kw] : 0.f;
  }
  if (tid < 48){
    float s1 = g1[tid] / sqrtf(v1[tid] + 1e-5f);
    sc1[tid] = s1; sh1[tid] = be1[tid] + (b1[tid] - m1[tid]) * s1;
    float s2 = g2[tid] / sqrtf(v2[tid] + 1e-5f);
    sc2[tid] = s2; sh2[tid] = be2[tid] + (b2[tid] - m2[tid]) * s2;
  }

  float acc[6][8];
  #pragma unroll
  for (int o = 0; o < 6; ++o)
    #pragma unroll
    for (int j = 0; j < 8; ++j) acc[o][j] = 0.f;

  for (int ch = 0; ch < 6; ++ch){
    int ci0 = ch * 8;
    __syncthreads();
    for (int idx = tid; idx < 3*8*240; idx += 256){
      int rr = idx / 1920;
      int rem = idx - rr*1920;
      int ci = rem / 240, w = rem - ci*240;
      int tt = t + rr - 1, f = w - 1;
      float val = 0.f;
      if (tt >= 0 && tt < 512 && f >= 0 && f < 229){
        int cg = ci0 + ci;
        float a = 0.f;
        #pragma unroll
        for (int dh = 0; dh < 3; ++dh){
          const float* mr = &mel5[(rr + dh)*240 + w];
          a = fmaf(mr[0], w1s[cg*12 + dh*4 + 0], a);
          a = fmaf(mr[1], w1s[cg*12 + dh*4 + 1], a);
          a = fmaf(mr[2], w1s[cg*12 + dh*4 + 2], a);
        }
        a = a * sc1[cg] + sh1[cg];
        val = a > 0.f ? a : 0.f;
      }
      act[idx] = val;
    }
    for (int idx = tid; idx < 48*8*12; idx += 256){
      int oc = idx / 96;
      int rem = idx - oc*96;
      int ci = rem / 12, q = rem - ci*12;
      int kh = q >> 2, kw = q & 3;
      w2s[idx] = (kw < 3) ? w2[(oc*48 + ci0 + ci)*9 + kh*3 + kw] : 0.f;
    }
    __syncthreads();
    if (tid < 232){
      for (int ci = 0; ci < 8; ++ci){
        #pragma unroll
        for (int kh = 0; kh < 3; ++kh){
          const float* ap = &act[(kh*8 + ci)*240 + f0];
          float4 A0 = *(const float4*)(ap);
          float4 A1v = *(const float4*)(ap + 4);
          float4 A2 = *(const float4*)(ap + 8);
          float L[12] = {A0.x,A0.y,A0.z,A0.w,A1v.x,A1v.y,A1v.z,A1v.w,A2.x,A2.y,A2.z,A2.w};
          #pragma unroll
          for (int o = 0; o < 6; ++o){
            float4 wv = *(const float4*)&w2s[((oc0 + o)*8 + ci)*12 + kh*4];
            #pragma unroll
            for (int j = 0; j < 8; ++j)
              acc[o][j] = fmaf(L[j+2], wv.z, fmaf(L[j+1], wv.y, fmaf(L[j], wv.x, acc[o][j])));
          }
        }
      }
    }
  }
  __syncthreads();
  if (tid < 232){
    #pragma unroll
    for (int o = 0; o < 6; ++o){
      int oc = oc0 + o;
      float s = sc2[oc], hs = sh2[oc];
      #pragma unroll
      for (int jj = 0; jj < 4; ++jj){
        int fp = fg*4 + jj;
        if (fp < 114){
          float v0 = acc[o][2*jj] * s + hs;   v0 = v0 > 0.f ? v0 : 0.f;
          float v1 = acc[o][2*jj+1] * s + hs; v1 = v1 > 0.f ? v1 : 0.f;
          cstore(&c2ch[((b*48 + oc)*130 + lt)*114 + fp], v0 > v1 ? v0 : v1);
        }
      }
    }
  }
}

__device__ void conv3_body(float* SH, int vb, int t0,
    const float* c2ch, const float* w3, const float* b3, const float* g3,
    const float* be3, const float* m3, const float* v3, float* c3p)
{
  float* act = SH;             // 3*8*128 = 3072
  float* w3s = SH + 3072;      // 96*8*12 = 9216
  float* sc  = SH + 12288; float* sh = SH + 12384;
  int tid = threadIdx.x;
  int b = vb >> 7, tl = vb & 127;
  __syncthreads();   // LDS reuse guard
  if (tid < 96){
    float s = g3[tid] / sqrtf(v3[tid] + 1e-5f);
    sc[tid] = s; sh[tid] = be3[tid] + (b3[tid] - m3[tid]) * s;
  }
  int fg = tid % 15, ocg = tid / 15;
  int f0 = fg * 8, oc0 = ocg * 6;
  float acc[6][8];
  #pragma unroll
  for (int o = 0; o < 6; ++o)
    #pragma unroll
    for (int j = 0; j < 8; ++j) acc[o][j] = 0.f;

  for (int ch = 0; ch < 6; ++ch){
    int ci0 = ch * 8;
    __syncthreads();
    for (int idx = tid; idx < 3*8*128; idx += 256){
      int rr = idx >> 10;
      int rem = idx & 1023;
      int ci = rem >> 7, w = rem & 127;
      int lt = tl + rr;
      int f = w - 1;
      float val = 0.f;
      if (f >= 0 && f < 114)
        val = cloadf(&c2ch[((b*48 + ci0 + ci)*130 + lt)*114 + f]);
      act[idx] = val;
    }
    for (int idx = tid; idx < 96*8*12; idx += 256){
      int oc = idx / 96;
      int rem = idx - oc*96;
      int ci = rem / 12, q = rem - ci*12;
      int kh = q >> 2, kw = q & 3;
      w3s[idx] = (kw < 3) ? w3[(oc*48 + ci0 + ci)*9 + kh*3 + kw] : 0.f;
    }
    __syncthreads();
    if (tid < 240){
      for (int ci = 0; ci < 8; ++ci){
        #pragma unroll
        for (int kh = 0; kh < 3; ++kh){
          const float* ap = &act[(kh*8 + ci)*128 + f0];
          float4 A0 = *(const float4*)(ap);
          float4 A1v = *(const float4*)(ap + 4);
          float4 A2 = *(const float4*)(ap + 8);
          float L[12] = {A0.x,A0.y,A0.z,A0.w,A1v.x,A1v.y,A1v.z,A1v.w,A2.x,A2.y,A2.z,A2.w};
          #pragma unroll
          for (int o = 0; o < 6; ++o){
            float4 wv = *(const float4*)&w3s[((oc0 + o)*8 + ci)*12 + kh*4];
            #pragma unroll
            for (int j = 0; j < 8; ++j)
              acc[o][j] = fmaf(L[j+2], wv.z, fmaf(L[j+1], wv.y, fmaf(L[j], wv.x, acc[o][j])));
          }
        }
      }
    }
  }
  __syncthreads();
  if (tid < 240){
    #pragma unroll
    for (int o = 0; o < 6; ++o){
      int oc = oc0 + o;
      float s = sc[oc], hs = sh[oc];
      #pragma unroll
      for (int jj = 0; jj < 4; ++jj){
        int fp = fg*4 + jj;
        if (fp < 57){
          float v0 = acc[o][2*jj] * s + hs;   v0 = v0 > 0.f ? v0 : 0.f;
          float v1 = acc[o][2*jj+1] * s + hs; v1 = v1 > 0.f ? v1 : 0.f;
          // rotating chunk-width c3p: tt & 127 == tl
          cstore(&c3p[((b*96 + oc)*128 + tl)*57 + fp], v0 > v1 ? v0 : v1);
        }
      }
    }
  }
}

__device__ void gemmfc_body(float* SH, int vb, int c,
    const float* c3p, const float* fcw, const float* fcb, float* ac)
{
  float* As = SH;          // 16*132
  float* Bs = SH + 2112;   // 16*132
  int tid = threadIdx.x;
  int bb = vb & 7, by = vb >> 3;        // vb in [0,48): 8 m-tiles x 6 n-tiles
  int m0 = (bb*4 + c) * 128, n0 = by * 128;
  int tm = (tid & 15) * 8, tn = (tid >> 4) * 8;
  float acc[8][8];
  #pragma unroll
  for (int i = 0; i < 8; ++i)
    #pragma unroll
    for (int j = 0; j < 8; ++j) acc[i][j] = 0.f;

  for (int k0 = 0; k0 < 5472; k0 += 16){
    __syncthreads();
    #pragma unroll
    for (int i = 0; i < 8; ++i){
      int idx = i*256 + tid;
      int k = idx & 15, mm = idx >> 4;
      int gk = k0 + k;
      int ci = (gk * 36793) >> 21;
      int f  = gk - ci*57;
      int gm = m0 + mm;
      int bb2 = gm >> 9, tt = gm & 511;
      As[k*132 + mm] = cloadf(&c3p[((bb2*96 + ci)*128 + (tt & 127))*57 + f]);
      Bs[k*132 + mm] = fcw[(n0 + mm)*5472 + gk];
    }
    __syncthreads();
    #pragma unroll
    for (int k = 0; k < 16; ++k){
      const float* arow = &As[k*132 + tm];
      const float* brow = &Bs[k*132 + tn];
      float4 a0 = *(const float4*)arow, a1 = *(const float4*)(arow + 4);
      float4 b0 = *(const float4*)brow, b1 = *(const float4*)(brow + 4);
      float av[8] = {a0.x,a0.y,a0.z,a0.w,a1.x,a1.y,a1.z,a1.w};
      float bv[8] = {b0.x,b0.y,b0.z,b0.w,b1.x,b1.y,b1.z,b1.w};
      #pragma unroll
      for (int i = 0; i < 8; ++i)
        #pragma unroll
        for (int j = 0; j < 8; ++j)
          acc[i][j] = fmaf(av[i], bv[j], acc[i][j]);
    }
  }
  __syncthreads();
  #pragma unroll
  for (int i = 0; i < 8; ++i){
    int gm = m0 + tm + i;
    #pragma unroll
    for (int j = 0; j < 8; ++j){
      int gn = n0 + tn + j;
      cstore(&ac[gm*768 + gn], acc[i][j] + fcb[gn]);
    }
  }
}

__device__ void gemma1_body(float* SH, int vb, int c,
    const float* ac, const float* wih1, const float* bih1,
    const float* bhh1, float* A1)
{
  float* As = SH;
  float* Bs = SH + 2112;
  int tid = threadIdx.x;
  int bb = vb & 7, by = vb >> 3;        // vb in [0,192): 8 m-tiles x 24 n-tiles
  int m0 = (bb*4 + c) * 128, n0 = by * 128;
  int tm = (tid & 15) * 8, tn = (tid >> 4) * 8;
  float acc[8][8];
  #pragma unroll
  for (int i = 0; i < 8; ++i)
    #pragma unroll
    for (int j = 0; j < 8; ++j) acc[i][j] = 0.f;

  for (int k0 = 0; k0 < 768; k0 += 16){
    __syncthreads();
    #pragma unroll
    for (int i = 0; i < 8; ++i){
      int idx = i*256 + tid;
      int k = idx & 15, mm = idx >> 4;
      int gk = k0 + k;
      As[k*132 + mm] = cloadf(&ac[(m0 + mm)*768 + gk]);
      Bs[k*132 + mm] = wih1[(n0 + mm)*944 + gk];
    }
    __syncthreads();
    #pragma unroll
    for (int k = 0; k < 16; ++k){
      const float* arow = &As[k*132 + tm];
      const float* brow = &Bs[k*132 + tn];
      float4 a0 = *(const float4*)arow, a1 = *(const float4*)(arow + 4);
      float4 b0 = *(const float4*)brow, b1 = *(const float4*)(brow + 4);
      float av[8] = {a0.x,a0.y,a0.z,a0.w,a1.x,a1.y,a1.z,a1.w};
      float bv[8] = {b0.x,b0.y,b0.z,b0.w,b1.x,b1.y,b1.z,b1.w};
      #pragma unroll
      for (int i = 0; i < 8; ++i)
        #pragma unroll
        for (int j = 0; j < 8; ++j)
          acc[i][j] = fmaf(av[i], bv[j], acc[i][j]);
    }
  }
  __syncthreads();
  #pragma unroll
  for (int i = 0; i < 8; ++i){
    int gm = m0 + tm + i;
    int tt = gm & 511, bb2 = gm >> 9;
    #pragma unroll
    for (int j = 0; j < 8; ++j){
      int gn = n0 + tn + j;
      cstore(&A1[tt*24576 + gn*8 + bb2], acc[i][j] + bih1[gn] + bhh1[gn]);
    }
  }
}

// ================= fused persistent kernel =================
// wid < 256 : recurrent WGs (R6's proven schedule + coherent A1 read and
//             per-chunk rdy gate).
// wid >= 256: prologue WGs (conv2f -> conv3 -> gemm_fc -> gemm_a1, chunked
//             by 128 timesteps, 2-hop pbar between stages, release rdy[c]).
// ALL cross-WG intermediates travel coherently (cstore/cload) — the R1/R6
// proven regime; no cache-maintenance instructions anywhere.
// 2 WGs/CU co-residency REQUIRED: __launch_bounds__(256,2), 71.9KB LDS.
#define S2 772
__global__ __launch_bounds__(256, 2) void fat_k(
    const float* __restrict__ mel,
    const float* __restrict__ w1, const float* __restrict__ b1,
    const float* __restrict__ g1, const float* __restrict__ be1,
    const float* __restrict__ m1, const float* __restrict__ v1,
    const float* __restrict__ w2, const float* __restrict__ b2,
    const float* __restrict__ g2, const float* __restrict__ be2,
    const float* __restrict__ m2, const float* __restrict__ v2,
    const float* __restrict__ w3, const float* __restrict__ b3,
    const float* __restrict__ g3, const float* __restrict__ be3,
    const float* __restrict__ m3, const float* __restrict__ v3,
    const float* __restrict__ fcw, const float* __restrict__ fcb,
    const float* __restrict__ wih1, const float* __restrict__ whh1,
    const float* __restrict__ bih1, const float* __restrict__ bhh1,
    const float* __restrict__ wih2, const float* __restrict__ whh2,
    const float* __restrict__ bih2, const float* __restrict__ bhh2,
    const float* __restrict__ postw, const float* __restrict__ postb,
    const float* __restrict__ embw,
    float* __restrict__ c2ch, float* __restrict__ c3p,
    float* __restrict__ ac, float* __restrict__ A1,
    float* __restrict__ xbuf, float* __restrict__ hbuf,
    unsigned* __restrict__ slt, unsigned* __restrict__ sy,
    unsigned* __restrict__ psy, unsigned* __restrict__ rdy,
    float* __restrict__ out)
{
  __shared__ float SH[17976];   // 71.9 KB union (rec layout is largest)
  const int wid = blockIdx.x, tid = threadIdx.x;

  if (wid >= 256){
    // ---------------- prologue path ----------------
    const int pid = wid - 256;
    unsigned pb = 0;
    for (int c = 0; c < 4; ++c){
      int t0 = c * 128;
      for (int vb = pid; vb < 8*130; vb += 256)
        conv2f_body(SH, vb, t0, mel, w1, b1, g1, be1, m1, v1,
                    w2, b2, g2, be2, m2, v2, c2ch);
      ++pb; gbar(psy, pb, pid);
      for (int vb = pid; vb < 8*128; vb += 256)
        conv3_body(SH, vb, t0, c2ch, w3, b3, g3, be3, m3, v3, c3p);
      ++pb; gbar(psy, pb, pid);
      for (int vb = pid; vb < 48; vb += 256)
        gemmfc_body(SH, vb, c, c3p, fcw, fcb, ac);
      ++pb; gbar(psy, pb, pid);
      for (int vb = pid; vb < 192; vb += 256)
        gemma1_body(SH, vb, c, ac, wih1, bih1, bhh1, A1);
      ++pb; gbar(psy, pb, pid);
      if (pid == 255 && tid == 0)
        __hip_atomic_store(&rdy[c], 1u, __ATOMIC_RELAXED,
                           __HIP_MEMORY_SCOPE_SYSTEM);
    }
    return;
  }

  // ---------------- recurrent path (R6 schedule) ----------------
  const int wg = wid;
  const int wv = tid >> 6, l = tid & 63;
  float* xs   = SH;            // 8*S2 = 6176
  float* h2s  = SH + 6176;     // 6176
  float* cvec = SH + 12352;    // 88*5*12 = 5280
  float* zbuf = SH + 17632;    // 96
  float* red2 = SH + 17728;    // 160
  unsigned* smax = (unsigned*)(SH + 17888);  // 88

  float wA[12][3];
  float wB[24][3];
  float wC[3][5];
  {
    int Rb = wv*768 + wg*3;
    #pragma unroll
    for (int ki = 0; ki < 12; ++ki){
      int k = l + (ki << 6);
      #pragma unroll
      for (int u = 0; u < 3; ++u)
        wA[ki][u] = whh1[(Rb + u)*768 + k];
    }
    #pragma unroll
    for (int ki = 0; ki < 24; ++ki){
      int k = l + (ki << 6);
      #pragma unroll
      for (int u = 0; u < 3; ++u)
        wB[ki][u] = (k < 768) ? wih2[(Rb + u)*768 + k] : whh2[(Rb + u)*768 + k - 768];
    }
  }
  if (wg < 88){
    #pragma unroll
    for (int kc = 0; kc < 3; ++kc)
      #pragma unroll
      for (int s = 0; s < 5; ++s)
        wC[kc][s] = postw[(wg*5 + s)*768 + tid + (kc << 8)];
  }
  float b2r = 0.f; int fR = 0, fb = 0;
  if (tid < 96){
    int g = tid / 24, rem = tid - g*24;
    int u = rem >> 3; fb = rem & 7;
    fR = g*768 + wg*3 + u;
    b2r = bih2[fR] + bhh2[fR];
  }
  float pbr = (wg < 88 && tid < 40) ? postb[wg*5 + (tid >> 3)] : 0.f;
  float c1r = 0.f, c2r = 0.f;

  // cvec[(p*5+s)*12 + (g*3+u)] = emb contribution of pitch p in state s to
  // this WG's gate row (g*768 + wg*3 + u). Computed once.
  for (int idx = tid; idx < 88*5*12; idx += 256){
    int p = idx / 60, rem = idx - p*60;
    int s = rem / 12, r = rem - s*12;
    int g = r / 3, u = r - g*3;
    int row = g*768 + wg*3 + u;
    cvec[idx] = wih1[row*944 + 768 + 2*p]     * embw[s*2]
              + wih1[row*944 + 768 + 2*p + 1] * embw[s*2 + 1];
  }
  for (int idx = tid; idx < 8*S2; idx += 256){ h2s[idx] = 0.f; xs[idx] = 0.f; }
  __syncthreads();

  unsigned bar = 0;

  for (int t = 0; t < 512; ++t){
    // chunk gate: A1 chunk (t>>7) must be released by the prologue
    if ((t & 127) == 0){
      if (tid == 0){
        const int c = t >> 7;
        while (__hip_atomic_load(&rdy[c], __ATOMIC_RELAXED,
                                 __HIP_MEMORY_SCOPE_SYSTEM) == 0)
          __builtin_amdgcn_s_sleep(1);
      }
      __syncthreads();
    }

    float* xn = xbuf + (t & 1) * 6144;
    float* hw = hbuf + (t & 1) * 6144;             // h2n(t)
    const float* hr = hbuf + ((t ^ 1) & 1) * 6144; // h2n(t-1)

    float a1v = 0.f;
    if (tid < 96) a1v = cloadf(&A1[t*24576 + fR*8 + fb]);

    // ---- PH1: load h2n(t-1); pitch WGs: logits(t-1) -> out/argmax/slot ----
    float r0[8], r1[8], r2[8];
    #pragma unroll
    for (int q = 0; q < 8; ++q){ r0[q] = 0.f; r1[q] = 0.f; r2[q] = 0.f; }
    if (t > 0){
      #pragma unroll
      for (int q = 0; q < 4; ++q){
        cload64(hr + (tid      )*8 + 2*q, r0[2*q], r0[2*q+1]);
        cload64(hr + (tid + 256)*8 + 2*q, r1[2*q], r1[2*q+1]);
        cload64(hr + (tid + 512)*8 + 2*q, r2[2*q], r2[2*q+1]);
      }
      if (wg < 88){
        float accL[5][8];
        #pragma unroll
        for (int s = 0; s < 5; ++s)
          #pragma unroll
          for (int j = 0; j < 8; ++j)
            accL[s][j] = fmaf(wC[2][s], r2[j],
                         fmaf(wC[1][s], r1[j], wC[0][s]*r0[j]));
        #pragma unroll
        for (int s = 0; s < 5; ++s)
          #pragma unroll
          for (int j = 0; j < 8; ++j){
            float v = accL[s][j];
            v += __shfl_xor(v, 1);  v += __shfl_xor(v, 2);  v += __shfl_xor(v, 4);
            v += __shfl_xor(v, 8);  v += __shfl_xor(v, 16); v += __shfl_xor(v, 32);
            if (l == 0) red2[(s*8 + j)*4 + wv] = v;
          }
        __syncthreads();
        if (tid < 40){
          float sum = red2[tid*4] + red2[tid*4 + 1] + red2[tid*4 + 2] + red2[tid*4 + 3] + pbr;
          int s = tid >> 3, bb = tid & 7;
          out[bb*225280 + (t-1)*440 + wg*5 + s] = sum;
          zbuf[tid] = sum;
        }
        __syncthreads();
        int bs = 0;
        if (tid < 8){
          float best = zbuf[tid];
          #pragma unroll
          for (int s = 1; s < 5; ++s){
            float v = zbuf[s*8 + tid];
            if (v > best){ best = v; bs = s; }   // first max wins (jnp.argmax)
          }
        }
        if (wv == 0){
          unsigned lo = 0;
          #pragma unroll
          for (int b = 0; b < 8; ++b)
            lo |= (unsigned)(__shfl(bs, b) & 7) << (4*b);
          if (l == 0){
            unsigned long long pv =
                ((unsigned long long)(unsigned)t << 32) | (unsigned long long)lo;
            cstoreu64((unsigned long long*)slt + ((size_t)(t & 1)*88 + wg)*8, pv);
          }
        }
      }
    }

    // ---- PH2: A-dots gates1(t) from xs = h1(t-1) (hides PH1 loads) ----
    float acc1[3][8];
    #pragma unroll
    for (int u = 0; u < 3; ++u)
      #pragma unroll
      for (int j = 0; j < 8; ++j) acc1[u][j] = 0.f;
    #pragma unroll
    for (int ki = 0; ki < 12; ++ki){
      int k = l + (ki << 6);
      float x0 = xs[k],        x1 = xs[S2 + k],   x2 = xs[2*S2 + k], x3 = xs[3*S2 + k];
      float x4 = xs[4*S2 + k], x5 = xs[5*S2 + k], x6 = xs[6*S2 + k], x7 = xs[7*S2 + k];
      #pragma unroll
      for (int u = 0; u < 3; ++u){
        float w = wA[ki][u];
        acc1[u][0] = fmaf(w, x0, acc1[u][0]);
        acc1[u][1] = fmaf(w, x1, acc1[u][1]);
        acc1[u][2] = fmaf(w, x2, acc1[u][2]);
        acc1[u][3] = fmaf(w, x3, acc1[u][3]);
        acc1[u][4] = fmaf(w, x4, acc1[u][4]);
        acc1[u][5] = fmaf(w, x5, acc1[u][5]);
        acc1[u][6] = fmaf(w, x6, acc1[u][6]);
        acc1[u][7] = fmaf(w, x7, acc1[u][7]);
      }
    }

    // ---- PH3: stage h2s; reduce; poll slots; emb; cell1; bar1 ----
    __syncthreads();   // S1: PH1's zbuf/red2 readers done; B(t-1) zbuf done
    #pragma unroll
    for (int p = 0; p < 8; ++p){
      h2s[p*S2 + tid]       = r0[p];
      h2s[p*S2 + tid + 256] = r1[p];
      h2s[p*S2 + tid + 512] = r2[p];
    }
    #pragma unroll
    for (int u = 0; u < 3; ++u)
      #pragma unroll
      for (int j = 0; j < 8; ++j){
        float s = acc1[u][j];
        s += __shfl_xor(s, 1);  s += __shfl_xor(s, 2);  s += __shfl_xor(s, 4);
        s += __shfl_xor(s, 8);  s += __shfl_xor(s, 16); s += __shfl_xor(s, 32);
        if (l == 0) zbuf[wv*24 + u*8 + j] = s;
      }
    // wave0 polls the 88 argmax slot atoms (parity t&1, tag >= t; t=0
    // passes on memset zeros). Producers wrote them in PH1 of this same
    // iteration (right after bar2(t-1)), so this is normally fresh.
    if (wv == 0){
      const unsigned long long* sl =
          (const unsigned long long*)slt + (size_t)(t & 1) * 88 * 8;
      unsigned lo0 = 0, lo1 = 0;
      for (;;){
        unsigned long long v0 = cloadu64(&sl[l*8]);
        unsigned long long v1 = 0xffffffffffffffffull;
        if (l < 24) v1 = cloadu64(&sl[(64 + l)*8]);
        unsigned t0v = (unsigned)(v0 >> 32);
        unsigned t1v = (unsigned)(v1 >> 32);
        unsigned mn = t0v < t1v ? t0v : t1v;
        if (__all(mn >= (unsigned)t)){ lo0 = (unsigned)v0; lo1 = (unsigned)v1; break; }
        __builtin_amdgcn_s_sleep(1);
      }
      smax[l] = lo0;
      if (l < 24) smax[64 + l] = lo1;
    }
    __syncthreads();   // S2
    if (tid < 96){
      int g = tid / 24;
      int rowidx = g*3 + ((tid - g*24) >> 3);
      int b = tid & 7;
      float z = zbuf[tid] + a1v;
      for (int p = 0; p < 88; ++p){
        int s = (smax[p] >> (b*4)) & 7;
        z += cvec[(p*5 + s)*12 + rowidx];
      }
      zbuf[tid] = z;
    }
    __syncthreads();   // S3
    if (tid < 24){
      float zi = zbuf[tid], zf = zbuf[24 + tid], zg = zbuf[48 + tid], zo = zbuf[72 + tid];
      c1r = sigm(zf)*c1r + sigm(zi)*tanhf(zg);
      float hh = sigm(zo)*tanhf(c1r);
      cstore(&xn[wg*24 + tid], hh);   // plain coherent f32, idx = row*8+b
    }
    ++bar; gbar(sy, bar, wg);

    // ---- PH4: B: gates2 = h1n @ wih2.T + h2(t-1)[h2s] @ whh2.T + b ----
    {
      float sa[12], sb[12];
      #pragma unroll
      for (int i = 0; i < 12; ++i){
        int idx = tid + (i << 8);
        cload64(xn + 2*idx, sa[i], sb[i]);
      }
      float acc[3][8];
      #pragma unroll
      for (int u = 0; u < 3; ++u)
        #pragma unroll
        for (int j = 0; j < 8; ++j) acc[u][j] = 0.f;
      // h2 half first: operands already in LDS, hides the loads above
      #pragma unroll
      for (int ki = 12; ki < 24; ++ki){
        int k = l + ((ki - 12) << 6);
        float x0 = h2s[k],        x1 = h2s[S2 + k],   x2 = h2s[2*S2 + k], x3 = h2s[3*S2 + k];
        float x4 = h2s[4*S2 + k], x5 = h2s[5*S2 + k], x6 = h2s[6*S2 + k], x7 = h2s[7*S2 + k];
        #pragma unroll
        for (int u = 0; u < 3; ++u){
          float w = wB[ki][u];
          acc[u][0] = fmaf(w, x0, acc[u][0]);
          acc[u][1] = fmaf(w, x1, acc[u][1]);
          acc[u][2] = fmaf(w, x2, acc[u][2]);
          acc[u][3] = fmaf(w, x3, acc[u][3]);
          acc[u][4] = fmaf(w, x4, acc[u][4]);
          acc[u][5] = fmaf(w, x5, acc[u][5]);
          acc[u][6] = fmaf(w, x6, acc[u][6]);
          acc[u][7] = fmaf(w, x7, acc[u][7]);
        }
      }
      #pragma unroll
      for (int i = 0; i < 12; ++i){
        int idx = tid + (i << 8);
        int k = idx >> 2, p = (idx & 3) << 1;
        xs[p*S2 + k]       = sa[i];
        xs[(p + 1)*S2 + k] = sb[i];
      }
      __syncthreads();
      #pragma unroll
      for (int ki = 0; ki < 12; ++ki){
        int k = l + (ki << 6);
        float x0 = xs[k],        x1 = xs[S2 + k],   x2 = xs[2*S2 + k], x3 = xs[3*S2 + k];
        float x4 = xs[4*S2 + k], x5 = xs[5*S2 + k], x6 = xs[6*S2 + k], x7 = xs[7*S2 + k];
        #pragma unroll
        for (int u = 0; u < 3; ++u){
          float w = wB[ki][u];
          acc[u][0] = fmaf(w, x0, acc[u][0]);
          acc[u][1] = fmaf(w, x1, acc[u][1]);
          acc[u][2] = fmaf(w, x2, acc[u][2]);
          acc[u][3] = fmaf(w, x3, acc[u][3]);
          acc[u][4] = fmaf(w, x4, acc[u][4]);
          acc[u][5] = fmaf(w, x5, acc[u][5]);
          acc[u][6] = fmaf(w, x6, acc[u][6]);
          acc[u][7] = fmaf(w, x7, acc[u][7]);
        }
      }
      #pragma unroll
      for (int u = 0; u < 3; ++u)
        #pragma unroll
        for (int j = 0; j < 8; ++j){
          float s = acc[u][j];
          s += __shfl_xor(s, 1);  s += __shfl_xor(s, 2);  s += __shfl_xor(s, 4);
          s += __shfl_xor(s, 8);  s += __shfl_xor(s, 16); s += __shfl_xor(s, 32);
          if (l == 0) zbuf[wv*24 + u*8 + j] = s;
        }
      __syncthreads();
      if (tid < 96)
        zbuf[tid] += b2r;
      __syncthreads();
      if (tid < 24){
        float zi = zbuf[tid], zf = zbuf[24 + tid], zg = zbuf[48 + tid], zo = zbuf[72 + tid];
        c2r = sigm(zf)*c2r + sigm(zi)*tanhf(zg);
        float hh = sigm(zo)*tanhf(c2r);
        cstore(&hw[wg*24 + tid], hh);   // plain coherent f32
      }
      ++bar; gbar(sy, bar, wg);
    }
  }

  // ---- epilogue: logits(511) (h2n(511) in parity 1, fresh after bar2) ----
  if (wg < 88){
    const float* hr = hbuf + 6144;   // parity 511&1 = 1
    float r0[8], r1[8], r2[8];
    #pragma unroll
    for (int q = 0; q < 4; ++q){
      cload64(hr + (tid      )*8 + 2*q, r0[2*q], r0[2*q+1]);
      cload64(hr + (tid + 256)*8 + 2*q, r1[2*q], r1[2*q+1]);
      cload64(hr + (tid + 512)*8 + 2*q, r2[2*q], r2[2*q+1]);
    }
    float accL[5][8];
    #pragma unroll
    for (int s = 0; s < 5; ++s)
      #pragma unroll
      for (int j = 0; j < 8; ++j)
        accL[s][j] = fmaf(wC[2][s], r2[j],
                     fmaf(wC[1][s], r1[j], wC[0][s]*r0[j]));
    #pragma unroll
    for (int s = 0; s < 5; ++s)
      #pragma unroll
      for (int j = 0; j < 8; ++j){
        float v = accL[s][j];
        v += __shfl_xor(v, 1);  v += __shfl_xor(v, 2);  v += __shfl_xor(v, 4);
        v += __shfl_xor(v, 8);  v += __shfl_xor(v, 16); v += __shfl_xor(v, 32);
        if (l == 0) red2[(s*8 + j)*4 + wv] = v;
      }
    __syncthreads();
    if (tid < 40){
      float sum = red2[tid*4] + red2[tid*4 + 1] + red2[tid*4 + 2] + red2[tid*4 + 3] + pbr;
      int s = tid >> 3, bb = tid & 7;
      out[bb*225280 + 511*440 + wg*5 + s] = sum;
    }
  }
}

extern "C" void kernel_launch(void* const* d_in, const int* in_sizes, int n_in,
                              void* d_out, int out_size, void* d_ws, size_t ws_size,
                              hipStream_t stream)
{
  (void)in_sizes; (void)n_in; (void)out_size; (void)ws_size;
  const float* mel  = (const float*)d_in[0];
  const float* w1   = (const float*)d_in[1];
  const float* b1   = (const float*)d_in[2];
  const float* g1   = (const float*)d_in[3];
  const float* be1  = (const float*)d_in[4];
  const float* m1   = (const float*)d_in[5];
  const float* v1   = (const float*)d_in[6];
  const float* w2   = (const float*)d_in[7];
  const float* b2   = (const float*)d_in[8];
  const float* g2   = (const float*)d_in[9];
  const float* be2  = (const float*)d_in[10];
  const float* m2   = (const float*)d_in[11];
  const float* v2   = (const float*)d_in[12];
  const float* w3   = (const float*)d_in[13];
  const float* b3   = (const float*)d_in[14];
  const float* g3   = (const float*)d_in[15];
  const float* be3  = (const float*)d_in[16];
  const float* m3   = (const float*)d_in[17];
  const float* v3   = (const float*)d_in[18];
  const float* fcw  = (const float*)d_in[19];
  const float* fcb  = (const float*)d_in[20];
  const float* wih1 = (const float*)d_in[21];
  const float* whh1 = (const float*)d_in[22];
  const float* bih1 = (const float*)d_in[23];
  const float* bhh1 = (const float*)d_in[24];
  const float* wih2 = (const float*)d_in[25];
  const float* whh2 = (const float*)d_in[26];
  const float* bih2 = (const float*)d_in[27];
  const float* bhh2 = (const float*)d_in[28];
  const float* postw= (const float*)d_in[29];
  const float* postb= (const float*)d_in[30];
  const float* embw = (const float*)d_in[31];

  float* ws    = (float*)d_ws;
  float* c2ch  = ws + OF_C2CH;
  float* c3p   = ws + OF_C3P;
  float* ac    = ws + OF_AC;
  float* A1    = ws + OF_A1;
  float* st    = ws + OF_ST;
  float* xbuf  = st;
  float* hbuf  = st + 12288;
  unsigned* slt = (unsigned*)(st + 24576);
  unsigned* sy  = (unsigned*)(st + 27392);
  unsigned* psy = (unsigned*)(ws + OF_PSY);
  unsigned* rdy = (unsigned*)(ws + OF_RDY);
  float* outp  = (float*)d_out;

  // zero exchange state + rec barrier + prologue barrier + chunk flags
  hipMemsetAsync(ws + OF_ST, 0, (35600 + 8208 + 16) * sizeof(float), stream);

  fat_k<<<dim3(512), dim3(256), 0, stream>>>(
      mel, w1, b1, g1, be1, m1, v1, w2, b2, g2, be2, m2, v2,
      w3, b3, g3, be3, m3, v3, fcw, fcb,
      wih1, whh1, bih1, bhh1, wih2, whh2, bih2, bhh2,
      postw, postb, embw,
      c2ch, c3p, ac, A1, xbuf, hbuf, slt, sy, psy, rdy, outp);
}